// Round 5
// baseline (2579.723 us; speedup 1.0000x reference)
//
#include <hip/hip_runtime.h>
#include <math.h>

#define TOK 4096      // B*L
#define BSZ 2
#define SEQ 2048
#define DM  1024
#define DI  2048

__device__ __forceinline__ float softplus_f(float x) {
    return fmaxf(x, 0.f) + log1pf(expf(-fabsf(x)));
}
__device__ __forceinline__ float silu_f(float x) {
    return x / (1.f + expf(-x));
}

// ---------------------------------------------------------------------------
// GEMM: C[M,N] = A[M,K] * B[N,K]^T, fp32 in/out, fp32 accumulate.
// 128x128 tile, 256 threads, 8x8 per thread, BK=8.
// EPI=1: silu both halves, split n<DI -> C0 (x_path) else C1 (silu z).
// EPI=0: plain store C0[m*N+n].  Output dtype: FP32 (d_out is float!).
// ---------------------------------------------------------------------------
template <int EPI>
__global__ __launch_bounds__(256) void gemm_bt(
    const float* __restrict__ A, const float* __restrict__ B,
    int M, int N, int K,
    float* __restrict__ C0, float* __restrict__ C1)
{
    __shared__ float As[8][128];
    __shared__ float Bs[8][128];
    int t = threadIdx.x;
    int m0 = blockIdx.y * 128, n0 = blockIdx.x * 128;
    int ty = t >> 4, tx = t & 15;
    int cm = ty * 8, cn = tx * 8;

    float acc[8][8];
#pragma unroll
    for (int i = 0; i < 8; i++)
#pragma unroll
        for (int j = 0; j < 8; j++) acc[i][j] = 0.f;

    int lr = t >> 1;          // 0..127 row within tile
    int lk = (t & 1) * 4;     // 0 or 4
    const float* Ap = A + (size_t)(m0 + lr) * K + lk;
    const float* Bp = B + (size_t)(n0 + lr) * K + lk;

    for (int k0 = 0; k0 < K; k0 += 8) {
        float4 av = *(const float4*)(Ap + k0);
        float4 bv = *(const float4*)(Bp + k0);
        __syncthreads();
        As[lk + 0][lr] = av.x; As[lk + 1][lr] = av.y;
        As[lk + 2][lr] = av.z; As[lk + 3][lr] = av.w;
        Bs[lk + 0][lr] = bv.x; Bs[lk + 1][lr] = bv.y;
        Bs[lk + 2][lr] = bv.z; Bs[lk + 3][lr] = bv.w;
        __syncthreads();
#pragma unroll
        for (int k = 0; k < 8; k++) {
            float4 a0 = *(const float4*)&As[k][cm];
            float4 a1 = *(const float4*)&As[k][cm + 4];
            float4 b0 = *(const float4*)&Bs[k][cn];
            float4 b1 = *(const float4*)&Bs[k][cn + 4];
            float a[8] = {a0.x, a0.y, a0.z, a0.w, a1.x, a1.y, a1.z, a1.w};
            float b[8] = {b0.x, b0.y, b0.z, b0.w, b1.x, b1.y, b1.z, b1.w};
#pragma unroll
            for (int i = 0; i < 8; i++)
#pragma unroll
                for (int j = 0; j < 8; j++)
                    acc[i][j] = fmaf(a[i], b[j], acc[i][j]);
        }
    }

#pragma unroll
    for (int i = 0; i < 8; i++) {
        int m = m0 + cm + i;
#pragma unroll
        for (int j = 0; j < 8; j++) {
            int n = n0 + cn + j;
            float v = acc[i][j];
            if (EPI == 1) {
                v = silu_f(v);
                if (n < DI) C0[(size_t)m * DI + n] = v;
                else        C1[(size_t)m * DI + (n - DI)] = v;
            } else {
                C0[(size_t)m * N + n] = v;
            }
        }
    }
}

// ---------------------------------------------------------------------------
// Per-token: ssm = x_path_row . W_x^T (34 outputs), RMSNorm(B,C), dt_in, lam,
// mean_dt. One block (256 thr) per token.
// ---------------------------------------------------------------------------
__global__ __launch_bounds__(256) void ssm_kernel(
    const float* __restrict__ x_path, const float* __restrict__ W_x,
    const float* __restrict__ W_dt, const float* __restrict__ b_dt,
    const float* __restrict__ B_bias, const float* __restrict__ C_bias,
    const float* __restrict__ B_nw, const float* __restrict__ C_nw,
    float* __restrict__ Bn, float* __restrict__ Cn,
    float* __restrict__ dt_in, float* __restrict__ lam, float* __restrict__ mean_dt)
{
    __shared__ float red[34 * 4];
    __shared__ float ssm_v[34];
    __shared__ float sh_dtin;
    int tok = blockIdx.x;
    int t = threadIdx.x;
    int w = t >> 6;
    const float* xrow = x_path + (size_t)tok * DI;

    float acc[34];
#pragma unroll
    for (int s = 0; s < 34; s++) acc[s] = 0.f;
#pragma unroll
    for (int j = 0; j < 8; j++) {
        int e = j * 256 + t;
        float xv = xrow[e];
#pragma unroll
        for (int s = 0; s < 34; s++)
            acc[s] = fmaf(xv, W_x[s * DI + e], acc[s]);
    }
#pragma unroll
    for (int s = 0; s < 34; s++) {
        float v = acc[s];
        for (int off = 32; off; off >>= 1) v += __shfl_down(v, off);
        if ((t & 63) == 0) red[s * 4 + w] = v;
    }
    __syncthreads();
    if (t < 34) ssm_v[t] = red[t * 4] + red[t * 4 + 1] + red[t * 4 + 2] + red[t * 4 + 3];
    __syncthreads();
    if (t == 0) {
        float bb, ms;
        ms = 0.f;
        for (int s = 0; s < 16; s++) { bb = ssm_v[s] + B_bias[s]; ms += bb * bb; }
        float r = rsqrtf(ms * (1.f / 16.f) + 1.1920928955078125e-7f);
        for (int s = 0; s < 16; s++) Bn[tok * 16 + s] = (ssm_v[s] + B_bias[s]) * r * B_nw[s];
        ms = 0.f;
        for (int s = 0; s < 16; s++) { bb = ssm_v[16 + s] + C_bias[s]; ms += bb * bb; }
        r = rsqrtf(ms * (1.f / 16.f) + 1.1920928955078125e-7f);
        for (int s = 0; s < 16; s++) Cn[tok * 16 + s] = (ssm_v[16 + s] + C_bias[s]) * r * C_nw[s];
        float dv = ssm_v[32];
        dt_in[tok] = dv;
        sh_dtin = dv;
        lam[tok] = 1.f / (1.f + expf(-ssm_v[33]));
    }
    __syncthreads();
    float dv = sh_dtin;
    float part = 0.f;
#pragma unroll
    for (int j = 0; j < 8; j++) {
        int e = j * 256 + t;
        part += softplus_f(fmaf(dv, W_dt[e], b_dt[e]));
    }
    for (int off = 32; off; off >>= 1) part += __shfl_down(part, off);
    __syncthreads();
    if ((t & 63) == 0) red[w] = part;
    __syncthreads();
    if (t == 0) mean_dt[tok] = (red[0] + red[1] + red[2] + red[3]) * (1.f / 2048.f);
}

// ---------------------------------------------------------------------------
// Inclusive cumsum of mean_dt in fp64 (phase coherence insurance).
// ---------------------------------------------------------------------------
__global__ __launch_bounds__(256) void cumsum_kernel(
    const float* __restrict__ mean_dt, double* __restrict__ cum_dt)
{
    __shared__ double tot[256];
    __shared__ double pre[256];
    int b = blockIdx.x, t = threadIdx.x;
    const float* in = mean_dt + b * SEQ;
    double* out = cum_dt + b * SEQ;
    double v[8], sum = 0.0;
#pragma unroll
    for (int i = 0; i < 8; i++) { sum += (double)in[t * 8 + i]; v[i] = sum; }
    tot[t] = sum;
    __syncthreads();
    if (t == 0) { double r = 0.0; for (int i = 0; i < 256; i++) { pre[i] = r; r += tot[i]; } }
    __syncthreads();
    double off = pre[t];
#pragma unroll
    for (int i = 0; i < 8; i++) out[t * 8 + i] = off + v[i];
}

// ---------------------------------------------------------------------------
// RoPE, fp64 angles/trig (only 32K angles — negligible cost).
// ---------------------------------------------------------------------------
__global__ __launch_bounds__(256) void rope_kernel(
    const float* __restrict__ Bn, const float* __restrict__ Cn,
    const double* __restrict__ cum_dt, const float* __restrict__ rope_f,
    float* __restrict__ Br, float* __restrict__ Cr)
{
    int g = blockIdx.x * 256 + threadIdx.x;  // 0 .. TOK*8-1
    int tok = g >> 3, i = g & 7;
    double xf = (double)rope_f[i];
    double f = (xf > 0.0) ? xf + log1p(exp(-xf)) : log1p(exp(xf));  // softplus fp64
    double ang = cum_dt[tok] * f;
    float ca = (float)cos(ang), sa = (float)sin(ang);
    int base = tok * 16 + 2 * i;
    float be = Bn[base], bo = Bn[base + 1];
    Br[base]     = be * ca - bo * sa;
    Br[base + 1] = be * sa + bo * ca;
    float ce = Cn[base], co = Cn[base + 1];
    Cr[base]     = ce * ca - co * sa;
    Cr[base + 1] = ce * sa + co * ca;
}

// ---------------------------------------------------------------------------
// Sequential scan. 16 lanes per channel (one per state s); 16 channels per
// block of 256. Fused epilogue: y = (scan_y + x_path*D) * silu_z. All fp32.
// ---------------------------------------------------------------------------
__global__ __launch_bounds__(256) void scan_kernel(
    const float* __restrict__ x_path, const float* __restrict__ zs,
    const float* __restrict__ Br, const float* __restrict__ Cr,
    const float* __restrict__ dt_in, const float* __restrict__ lam,
    const float* __restrict__ W_dt, const float* __restrict__ b_dt,
    const float* __restrict__ A_log, const float* __restrict__ Dw,
    float* __restrict__ y)
{
    int t = threadIdx.x;
    int s = t & 15;
    int c = blockIdx.x * 16 + (t >> 4);   // channel = b*DI + e
    int b = c >> 11;
    int e = c & (DI - 1);
    float wdt = W_dt[e];
    float bdt = b_dt[e];
    float Df  = Dw[e];
    float Ae  = fminf(-expf(A_log[e * 16 + s]), -1e-4f);
    float h = 0.f, Bxp = 0.f;
    int tok0 = b * SEQ;
    for (int l = 0; l < SEQ; ++l) {
        int tok = tok0 + l;
        size_t xi = (size_t)tok * DI + e;
        float xv  = x_path[xi];
        float dti = dt_in[tok];
        float lm  = lam[tok];
        float brs = Br[tok * 16 + s];
        float crs = Cr[tok * 16 + s];
        float dt = softplus_f(fmaf(dti, wdt, bdt));
        float dA = expf(Ae * dt);
        float Bx = brs * xv;
        float u = (l == 0) ? dt * Bx
                           : ((1.f - lm) * dt * dA * Bxp + lm * dt * Bx);
        h = fmaf(dA, h, u);
        Bxp = Bx;
        float p = h * crs;
        p += __shfl_xor(p, 1);
        p += __shfl_xor(p, 2);
        p += __shfl_xor(p, 4);
        p += __shfl_xor(p, 8);
        if (s == 0) {
            float zv = zs[xi];
            y[xi] = (p + xv * Df) * zv;
        }
    }
}

// ---------------------------------------------------------------------------
extern "C" void kernel_launch(void* const* d_in, const int* in_sizes, int n_in,
                              void* d_out, int out_size, void* d_ws, size_t ws_size,
                              hipStream_t stream)
{
    const float* x      = (const float*)d_in[0];
    const float* W_in   = (const float*)d_in[1];
    const float* W_x    = (const float*)d_in[2];
    const float* W_dt   = (const float*)d_in[3];
    const float* b_dt   = (const float*)d_in[4];
    const float* A_log  = (const float*)d_in[5];
    const float* B_bias = (const float*)d_in[6];
    const float* C_bias = (const float*)d_in[7];
    const float* B_nw   = (const float*)d_in[8];
    const float* C_nw   = (const float*)d_in[9];
    const float* rope_f = (const float*)d_in[10];
    const float* Dw     = (const float*)d_in[11];
    const float* W_out  = (const float*)d_in[12];
    float* out = (float*)d_out;          // reference output dtype: FP32

    char* p = (char*)d_ws;
    const size_t BIGF = (size_t)TOK * DI * 4;         // 33.5 MiB each (fp32)
    float* x_path = (float*)(p);
    float* zs     = (float*)(p + BIGF);
    float* yb     = (float*)(p + 2 * BIGF);
    char* sm = p + 3 * BIGF;
    float*  Bn   = (float*)(sm);
    float*  Cn   = (float*)(sm + 262144);
    float*  Br   = (float*)(sm + 2 * 262144);
    float*  Cr   = (float*)(sm + 3 * 262144);
    float*  dtin = (float*)(sm + 4 * 262144);
    float*  lamv = (float*)(sm + 4 * 262144 + 16384);
    float*  mdt  = (float*)(sm + 4 * 262144 + 2 * 16384);
    double* cdt  = (double*)(sm + 4 * 262144 + 3 * 16384);  // 32 KiB fp64

    // 1. xz = x @ W_in^T, silu both halves -> x_path, silu(z)
    gemm_bt<1><<<dim3(32, 32), 256, 0, stream>>>(x, W_in, TOK, 2 * DI, DM, x_path, zs);
    // 2. per-token ssm projections + norms + dt/lam/mean_dt
    ssm_kernel<<<TOK, 256, 0, stream>>>(x_path, W_x, W_dt, b_dt, B_bias, C_bias,
                                        B_nw, C_nw, Bn, Cn, dtin, lamv, mdt);
    // 3. cumsum over sequence (fp64)
    cumsum_kernel<<<BSZ, 256, 0, stream>>>(mdt, cdt);
    // 4. rope (fp64 trig)
    rope_kernel<<<(TOK * 8) / 256, 256, 0, stream>>>(Bn, Cn, cdt, rope_f, Br, Cr);
    // 5. recurrence + fused epilogue -> y (fp32)
    scan_kernel<<<TOK * DI / (SEQ * 16), 256, 0, stream>>>(x_path, zs, Br, Cr, dtin, lamv,
                                                           W_dt, b_dt, A_log, Dw, yb);
    // 6. out = y @ W_out^T  (FP32 store to d_out)
    gemm_bt<0><<<dim3(DM / 128, TOK / 128), 256, 0, stream>>>(yb, W_out, TOK, DM, DI, out, nullptr);
}

// Round 6
// 1312.695 us; speedup vs baseline: 1.9652x; 1.9652x over previous
//
#include <hip/hip_runtime.h>
#include <math.h>

#define TOK 4096      // B*L
#define BSZ 2
#define SEQ 2048
#define DM  1024
#define DI  2048
#define NCH 32        // scan chunks per sequence
#define LC  64        // tokens per chunk (NCH*LC == SEQ)
#define NSTATE 65536  // BSZ*DI*16

__device__ __forceinline__ float softplus_f(float x) {
    return fmaxf(x, 0.f) + __logf(1.f + __expf(-fabsf(x)));
}
__device__ __forceinline__ float silu_f(float x) {
    return x / (1.f + __expf(-x));
}

// ---------------------------------------------------------------------------
// GEMM: C[M,N] = A[M,K] * B[N,K]^T, fp32, 128x128 tile, 8x8/thread, BK=8.
// EPI=1: silu both halves, split n<DI -> C0 (x_path) else C1 (silu z).
// EPI=0: plain store C0[m*N+n].
// ---------------------------------------------------------------------------
template <int EPI>
__global__ __launch_bounds__(256) void gemm_bt(
    const float* __restrict__ A, const float* __restrict__ B,
    int M, int N, int K,
    float* __restrict__ C0, float* __restrict__ C1)
{
    __shared__ float As[8][128];
    __shared__ float Bs[8][128];
    int t = threadIdx.x;
    int m0 = blockIdx.y * 128, n0 = blockIdx.x * 128;
    int ty = t >> 4, tx = t & 15;
    int cm = ty * 8, cn = tx * 8;

    float acc[8][8];
#pragma unroll
    for (int i = 0; i < 8; i++)
#pragma unroll
        for (int j = 0; j < 8; j++) acc[i][j] = 0.f;

    int lr = t >> 1;
    int lk = (t & 1) * 4;
    const float* Ap = A + (size_t)(m0 + lr) * K + lk;
    const float* Bp = B + (size_t)(n0 + lr) * K + lk;

    for (int k0 = 0; k0 < K; k0 += 8) {
        float4 av = *(const float4*)(Ap + k0);
        float4 bv = *(const float4*)(Bp + k0);
        __syncthreads();
        As[lk + 0][lr] = av.x; As[lk + 1][lr] = av.y;
        As[lk + 2][lr] = av.z; As[lk + 3][lr] = av.w;
        Bs[lk + 0][lr] = bv.x; Bs[lk + 1][lr] = bv.y;
        Bs[lk + 2][lr] = bv.z; Bs[lk + 3][lr] = bv.w;
        __syncthreads();
#pragma unroll
        for (int k = 0; k < 8; k++) {
            float4 a0 = *(const float4*)&As[k][cm];
            float4 a1 = *(const float4*)&As[k][cm + 4];
            float4 b0 = *(const float4*)&Bs[k][cn];
            float4 b1 = *(const float4*)&Bs[k][cn + 4];
            float a[8] = {a0.x, a0.y, a0.z, a0.w, a1.x, a1.y, a1.z, a1.w};
            float b[8] = {b0.x, b0.y, b0.z, b0.w, b1.x, b1.y, b1.z, b1.w};
#pragma unroll
            for (int i = 0; i < 8; i++)
#pragma unroll
                for (int j = 0; j < 8; j++)
                    acc[i][j] = fmaf(a[i], b[j], acc[i][j]);
        }
    }

#pragma unroll
    for (int i = 0; i < 8; i++) {
        int m = m0 + cm + i;
#pragma unroll
        for (int j = 0; j < 8; j++) {
            int n = n0 + cn + j;
            float v = acc[i][j];
            if (EPI == 1) {
                v = silu_f(v);
                if (n < DI) C0[(size_t)m * DI + n] = v;
                else        C1[(size_t)m * DI + (n - DI)] = v;
            } else {
                C0[(size_t)m * N + n] = v;
            }
        }
    }
}

// ---------------------------------------------------------------------------
// Per-token: ssm = x_path_row . W_x^T (34 outputs), RMSNorm(B,C), dt_in, lam,
// mean_dt. Also stores dt(tok,e)=softplus(dt_in*W_dt[e]+b_dt[e]) to dtbuf so
// the scan phases never recompute softplus. One block (256 thr) per token.
// ---------------------------------------------------------------------------
__global__ __launch_bounds__(256) void ssm_kernel(
    const float* __restrict__ x_path, const float* __restrict__ W_x,
    const float* __restrict__ W_dt, const float* __restrict__ b_dt,
    const float* __restrict__ B_bias, const float* __restrict__ C_bias,
    const float* __restrict__ B_nw, const float* __restrict__ C_nw,
    float* __restrict__ Bn, float* __restrict__ Cn,
    float* __restrict__ dt_in, float* __restrict__ lam, float* __restrict__ mean_dt,
    float* __restrict__ dtbuf)
{
    __shared__ float red[34 * 4];
    __shared__ float ssm_v[34];
    __shared__ float sh_dtin;
    int tok = blockIdx.x;
    int t = threadIdx.x;
    int w = t >> 6;
    const float* xrow = x_path + (size_t)tok * DI;

    float acc[34];
#pragma unroll
    for (int s = 0; s < 34; s++) acc[s] = 0.f;
#pragma unroll
    for (int j = 0; j < 8; j++) {
        int e = j * 256 + t;
        float xv = xrow[e];
#pragma unroll
        for (int s = 0; s < 34; s++)
            acc[s] = fmaf(xv, W_x[s * DI + e], acc[s]);
    }
#pragma unroll
    for (int s = 0; s < 34; s++) {
        float v = acc[s];
        for (int off = 32; off; off >>= 1) v += __shfl_down(v, off);
        if ((t & 63) == 0) red[s * 4 + w] = v;
    }
    __syncthreads();
    if (t < 34) ssm_v[t] = red[t * 4] + red[t * 4 + 1] + red[t * 4 + 2] + red[t * 4 + 3];
    __syncthreads();
    if (t == 0) {
        float bb, ms;
        ms = 0.f;
        for (int s = 0; s < 16; s++) { bb = ssm_v[s] + B_bias[s]; ms += bb * bb; }
        float r = rsqrtf(ms * (1.f / 16.f) + 1.1920928955078125e-7f);
        for (int s = 0; s < 16; s++) Bn[tok * 16 + s] = (ssm_v[s] + B_bias[s]) * r * B_nw[s];
        ms = 0.f;
        for (int s = 0; s < 16; s++) { bb = ssm_v[16 + s] + C_bias[s]; ms += bb * bb; }
        r = rsqrtf(ms * (1.f / 16.f) + 1.1920928955078125e-7f);
        for (int s = 0; s < 16; s++) Cn[tok * 16 + s] = (ssm_v[16 + s] + C_bias[s]) * r * C_nw[s];
        float dv = ssm_v[32];
        dt_in[tok] = dv;
        sh_dtin = dv;
        lam[tok] = 1.f / (1.f + __expf(-ssm_v[33]));
    }
    __syncthreads();
    float dv = sh_dtin;
    float part = 0.f;
#pragma unroll
    for (int j = 0; j < 8; j++) {
        int e = j * 256 + t;
        float dtv = softplus_f(fmaf(dv, W_dt[e], b_dt[e]));
        dtbuf[(size_t)tok * DI + e] = dtv;
        part += dtv;
    }
    for (int off = 32; off; off >>= 1) part += __shfl_down(part, off);
    __syncthreads();
    if ((t & 63) == 0) red[w] = part;
    __syncthreads();
    if (t == 0) mean_dt[tok] = (red[0] + red[1] + red[2] + red[3]) * (1.f / 2048.f);
}

// ---------------------------------------------------------------------------
// fp64 inclusive cumsum of mean_dt per batch (phase coherence).
// ---------------------------------------------------------------------------
__global__ __launch_bounds__(256) void cumsum_kernel(
    const float* __restrict__ mean_dt, double* __restrict__ cum_dt)
{
    __shared__ double tot[256];
    __shared__ double pre[256];
    int b = blockIdx.x, t = threadIdx.x;
    const float* in = mean_dt + b * SEQ;
    double* out = cum_dt + b * SEQ;
    double v[8], sum = 0.0;
#pragma unroll
    for (int i = 0; i < 8; i++) { sum += (double)in[t * 8 + i]; v[i] = sum; }
    tot[t] = sum;
    __syncthreads();
    if (t == 0) { double r = 0.0; for (int i = 0; i < 256; i++) { pre[i] = r; r += tot[i]; } }
    __syncthreads();
    double off = pre[t];
#pragma unroll
    for (int i = 0; i < 8; i++) out[t * 8 + i] = off + v[i];
}

// ---------------------------------------------------------------------------
// RoPE, fp64 angles/trig (32K threads — negligible).
// ---------------------------------------------------------------------------
__global__ __launch_bounds__(256) void rope_kernel(
    const float* __restrict__ Bn, const float* __restrict__ Cn,
    const double* __restrict__ cum_dt, const float* __restrict__ rope_f,
    float* __restrict__ Br, float* __restrict__ Cr)
{
    int g = blockIdx.x * 256 + threadIdx.x;  // 0 .. TOK*8-1
    int tok = g >> 3, i = g & 7;
    double xf = (double)rope_f[i];
    double f = (xf > 0.0) ? xf + log1p(exp(-xf)) : log1p(exp(xf));
    double ang = cum_dt[tok] * f;
    float ca = (float)cos(ang), sa = (float)sin(ang);
    int base = tok * 16 + 2 * i;
    float be = Bn[base], bo = Bn[base + 1];
    Br[base]     = be * ca - bo * sa;
    Br[base + 1] = be * sa + bo * ca;
    float ce = Cn[base], co = Cn[base + 1];
    Cr[base]     = ce * ca - co * sa;
    Cr[base + 1] = ce * sa + co * ca;
}

// ---------------------------------------------------------------------------
// Chunked scan, h_l = dA_l*h_{l-1} + u_l (linear recurrence).
// Phase A: per-chunk local scan (h0=0) + cumprod P.  8192 blocks.
// Phase B: serial chunk-boundary combine (65536 states x 31 steps).
// Phase C: re-run chunks from correct h_in, emit y + fused epilogue.
// Block = 16 channels x 16 states. dt comes precomputed from dtbuf.
// ---------------------------------------------------------------------------
__global__ __launch_bounds__(256) void scan_phaseA(
    const float* __restrict__ x_path, const float* __restrict__ dtbuf,
    const float* __restrict__ Br, const float* __restrict__ lam,
    const float* __restrict__ A_log,
    float* __restrict__ hA, float* __restrict__ PA)
{
    int t = threadIdx.x;
    int s = t & 15, cl = t >> 4;
    int ch = blockIdx.x * 16 + cl;          // 0..4095 = b*DI + e
    int b = ch >> 11, e = ch & (DI - 1);
    int c = blockIdx.y;
    float Ae = fminf(-__expf(A_log[e * 16 + s]), -1e-4f);
    int tok0 = b * SEQ + c * LC;
    const float* xp  = x_path + (size_t)tok0 * DI + e;
    const float* dp  = dtbuf  + (size_t)tok0 * DI + e;
    const float* brp = Br + (size_t)tok0 * 16 + s;
    const float* lp  = lam + tok0;
    float h = 0.f, P = 1.f, Bxp = 0.f;
    if (c > 0) Bxp = brp[-16] * xp[-DI];
    for (int i = 0; i < LC; i++) {
        float dt  = dp[(size_t)i * DI];
        float xv  = xp[(size_t)i * DI];
        float brs = brp[i * 16];
        float lm  = lp[i];
        float dA = __expf(Ae * dt);
        float Bx = brs * xv;
        float u = (c == 0 && i == 0) ? dt * Bx
                                     : (1.f - lm) * dt * dA * Bxp + lm * dt * Bx;
        h = fmaf(dA, h, u);
        P *= dA;
        Bxp = Bx;
    }
    size_t o = (size_t)c * NSTATE + (size_t)ch * 16 + s;
    hA[o] = h;
    PA[o] = P;
}

__global__ __launch_bounds__(256) void scan_phaseB(
    const float* __restrict__ hA, const float* __restrict__ PA,
    float* __restrict__ hin)
{
    int g = blockIdx.x * 256 + threadIdx.x;  // 0..65535 = ch*16+s
    float h = 0.f;
    hin[g] = 0.f;
    for (int c = 1; c < NCH; c++) {
        size_t o = (size_t)(c - 1) * NSTATE + g;
        h = fmaf(PA[o], h, hA[o]);
        hin[(size_t)c * NSTATE + g] = h;
    }
}

__global__ __launch_bounds__(256) void scan_phaseC(
    const float* __restrict__ x_path, const float* __restrict__ zs,
    const float* __restrict__ dtbuf,
    const float* __restrict__ Br, const float* __restrict__ Cr,
    const float* __restrict__ lam, const float* __restrict__ A_log,
    const float* __restrict__ Dw, const float* __restrict__ hin,
    float* __restrict__ y)
{
    int t = threadIdx.x;
    int s = t & 15, cl = t >> 4;
    int ch = blockIdx.x * 16 + cl;
    int b = ch >> 11, e = ch & (DI - 1);
    int c = blockIdx.y;
    float Ae = fminf(-__expf(A_log[e * 16 + s]), -1e-4f);
    float Df = Dw[e];
    int tok0 = b * SEQ + c * LC;
    const float* xp  = x_path + (size_t)tok0 * DI + e;
    const float* zp  = zs     + (size_t)tok0 * DI + e;
    const float* dp  = dtbuf  + (size_t)tok0 * DI + e;
    const float* brp = Br + (size_t)tok0 * 16 + s;
    const float* crp = Cr + (size_t)tok0 * 16 + s;
    const float* lp  = lam + tok0;
    float*       yp  = y + (size_t)tok0 * DI + e;
    float h = hin[(size_t)c * NSTATE + (size_t)ch * 16 + s];
    float Bxp = 0.f;
    if (c > 0) Bxp = brp[-16] * xp[-DI];
    for (int i = 0; i < LC; i++) {
        float dt  = dp[(size_t)i * DI];
        float xv  = xp[(size_t)i * DI];
        float brs = brp[i * 16];
        float crs = crp[i * 16];
        float lm  = lp[i];
        float dA = __expf(Ae * dt);
        float Bx = brs * xv;
        float u = (c == 0 && i == 0) ? dt * Bx
                                     : (1.f - lm) * dt * dA * Bxp + lm * dt * Bx;
        h = fmaf(dA, h, u);
        Bxp = Bx;
        float p = h * crs;
        p += __shfl_xor(p, 1);
        p += __shfl_xor(p, 2);
        p += __shfl_xor(p, 4);
        p += __shfl_xor(p, 8);
        if (s == 0) {
            float zv = zp[(size_t)i * DI];
            yp[(size_t)i * DI] = (p + xv * Df) * zv;
        }
    }
}

// ---------------------------------------------------------------------------
extern "C" void kernel_launch(void* const* d_in, const int* in_sizes, int n_in,
                              void* d_out, int out_size, void* d_ws, size_t ws_size,
                              hipStream_t stream)
{
    const float* x      = (const float*)d_in[0];
    const float* W_in   = (const float*)d_in[1];
    const float* W_x    = (const float*)d_in[2];
    const float* W_dt   = (const float*)d_in[3];
    const float* b_dt   = (const float*)d_in[4];
    const float* A_log  = (const float*)d_in[5];
    const float* B_bias = (const float*)d_in[6];
    const float* C_bias = (const float*)d_in[7];
    const float* B_nw   = (const float*)d_in[8];
    const float* C_nw   = (const float*)d_in[9];
    const float* rope_f = (const float*)d_in[10];
    const float* Dw     = (const float*)d_in[11];
    const float* W_out  = (const float*)d_in[12];
    float* out = (float*)d_out;          // fp32 output

    char* p = (char*)d_ws;
    const size_t BIGF = (size_t)TOK * DI * 4;         // 33.5 MB each
    float* x_path = (float*)(p);
    float* zs     = (float*)(p + BIGF);
    float* yb     = (float*)(p + 2 * BIGF);
    float* dtbuf  = (float*)(p + 3 * BIGF);
    char* sm = p + 4 * BIGF;
    float*  Bn   = (float*)(sm);
    float*  Cn   = (float*)(sm + 262144);
    float*  Br   = (float*)(sm + 2 * 262144);
    float*  Cr   = (float*)(sm + 3 * 262144);
    float*  dtin = (float*)(sm + 4 * 262144);
    float*  lamv = (float*)(sm + 4 * 262144 + 16384);
    float*  mdt  = (float*)(sm + 4 * 262144 + 2 * 16384);
    double* cdt  = (double*)(sm + 4 * 262144 + 3 * 16384);  // 32 KB
    char* sc = sm + 4 * 262144 + 3 * 16384 + 32768;
    const size_t SCS = (size_t)NCH * NSTATE * 4;            // 8.4 MB each
    float* hA  = (float*)(sc);
    float* PA  = (float*)(sc + SCS);
    float* hin = (float*)(sc + 2 * SCS);

    // 1. xz = x @ W_in^T, silu both halves -> x_path, silu(z)
    gemm_bt<1><<<dim3(32, 32), 256, 0, stream>>>(x, W_in, TOK, 2 * DI, DM, x_path, zs);
    // 2. ssm projections + norms + dt/lam/mean_dt + dtbuf
    ssm_kernel<<<TOK, 256, 0, stream>>>(x_path, W_x, W_dt, b_dt, B_bias, C_bias,
                                        B_nw, C_nw, Bn, Cn, dtin, lamv, mdt, dtbuf);
    // 3. cumsum over sequence (fp64)
    cumsum_kernel<<<BSZ, 256, 0, stream>>>(mdt, cdt);
    // 4. rope (fp64 trig)
    rope_kernel<<<(TOK * 8) / 256, 256, 0, stream>>>(Bn, Cn, cdt, rope_f, Br, Cr);
    // 5. chunked scan: A (local scans) -> B (boundary combine) -> C (emit y)
    scan_phaseA<<<dim3(4096 / 16, NCH), 256, 0, stream>>>(x_path, dtbuf, Br, lamv, A_log, hA, PA);
    scan_phaseB<<<NSTATE / 256, 256, 0, stream>>>(hA, PA, hin);
    scan_phaseC<<<dim3(4096 / 16, NCH), 256, 0, stream>>>(x_path, zs, dtbuf, Br, Cr,
                                                          lamv, A_log, Dw, hin, yb);
    // 6. out = y @ W_out^T (fp32 store)
    gemm_bt<0><<<dim3(DM / 128, TOK / 128), 256, 0, stream>>>(yb, W_out, TOK, DM, DI, out, nullptr);
}

// Round 7
// 752.067 us; speedup vs baseline: 3.4302x; 1.7454x over previous
//
#include <hip/hip_runtime.h>
#include <math.h>

#define TOK 4096      // B*L
#define BSZ 2
#define SEQ 2048
#define DM  1024
#define DI  2048
#define NCH 32        // scan chunks per sequence
#define LC  64        // tokens per chunk (NCH*LC == SEQ)
#define NSTATE 65536  // BSZ*DI*16

typedef __attribute__((ext_vector_type(8))) short bf16x8;      // MFMA A/B frag (4 VGPR)
typedef __attribute__((ext_vector_type(8))) unsigned short u16x8;
typedef __attribute__((ext_vector_type(4))) float f32x4;       // MFMA C/D frag

__device__ __forceinline__ float softplus_f(float x) {
    return fmaxf(x, 0.f) + __logf(1.f + __expf(-fabsf(x)));
}
__device__ __forceinline__ float silu_f(float x) {
    return x / (1.f + __expf(-x));
}
__device__ __forceinline__ unsigned short f2b(float f) {
    union { float f; unsigned int i; } v; v.f = f;
    unsigned int i = v.i;
    unsigned int r = (i + 0x7fffu + ((i >> 16) & 1u)) >> 16;
    return (unsigned short)r;
}

// ---------------------------------------------------------------------------
// fp32 -> bf16 convert (n multiple of 4).
// ---------------------------------------------------------------------------
__global__ __launch_bounds__(256) void f2bf_kernel(
    const float* __restrict__ in, unsigned short* __restrict__ out, int n)
{
    int g = blockIdx.x * 256 + threadIdx.x;
    int i = g * 4;
    if (i < n) {
        float4 v = *(const float4*)(in + i);
        ushort4 o;
        o.x = f2b(v.x); o.y = f2b(v.y); o.z = f2b(v.z); o.w = f2b(v.w);
        *(ushort4*)(out + i) = o;
    }
}

// ---------------------------------------------------------------------------
// MFMA GEMM: C[M,N] = A[M,K] * B[N,K]^T, bf16 in, fp32 out.
// 128x128 tile, 256 thr (4 waves in 2x2), 4x4 16x16x32 MFMA tiles per wave,
// BK=32. LDS staged via 16B register loads (m93 structure).
// Fragment maps (guide-verified): A/B [idx=lane&15][k=(lane>>4)*8+j],
// C/D col=lane&15, row=(lane>>4)*4+reg.
// EPI=1: silu; whole block routes to C0 (n0<DI, x_path) or C1 (zs) since
// n0 is a multiple of 128 and DI=2048. EPI=0: C0[m*N+n].
// ---------------------------------------------------------------------------
template <int EPI>
__global__ __launch_bounds__(256) void gemm_mfma(
    const unsigned short* __restrict__ A, const unsigned short* __restrict__ B,
    int M, int N, int K,
    float* __restrict__ C0, float* __restrict__ C1)
{
    __shared__ unsigned short As[128 * 32];
    __shared__ unsigned short Bs[128 * 32];
    int t = threadIdx.x;
    int lane = t & 63, wave = t >> 6;
    int wr = wave >> 1, wc = wave & 1;
    int m0 = blockIdx.y * 128, n0 = blockIdx.x * 128;

    int srow = t >> 2, skq = t & 3;        // staging: row 0..63, k-quad 0..3
    const unsigned short* Ap = A + (size_t)(m0 + srow) * K + skq * 8;
    const unsigned short* Bp = B + (size_t)(n0 + srow) * K + skq * 8;
    int sa = srow * 32 + skq * 8;          // LDS elem offset (row-major, ld=32)

    f32x4 acc[4][4];
#pragma unroll
    for (int i = 0; i < 4; i++)
#pragma unroll
        for (int j = 0; j < 4; j++) {
            f32x4 z = {0.f, 0.f, 0.f, 0.f};
            acc[i][j] = z;
        }

    int fr = lane & 15, fq = lane >> 4;    // fragment row, k-quad

    for (int k0 = 0; k0 < K; k0 += 32) {
        u16x8 a0 = *(const u16x8*)(Ap + k0);
        u16x8 a1 = *(const u16x8*)(Ap + (size_t)64 * K + k0);
        u16x8 b0 = *(const u16x8*)(Bp + k0);
        u16x8 b1 = *(const u16x8*)(Bp + (size_t)64 * K + k0);
        __syncthreads();
        *(u16x8*)&As[sa]           = a0;
        *(u16x8*)&As[sa + 64 * 32] = a1;
        *(u16x8*)&Bs[sa]           = b0;
        *(u16x8*)&Bs[sa + 64 * 32] = b1;
        __syncthreads();
        bf16x8 af[4], bfr[4];
#pragma unroll
        for (int i = 0; i < 4; i++)
            af[i] = *(const bf16x8*)&As[(wr * 64 + i * 16 + fr) * 32 + fq * 8];
#pragma unroll
        for (int j = 0; j < 4; j++)
            bfr[j] = *(const bf16x8*)&Bs[(wc * 64 + j * 16 + fr) * 32 + fq * 8];
#pragma unroll
        for (int i = 0; i < 4; i++)
#pragma unroll
            for (int j = 0; j < 4; j++)
                acc[i][j] = __builtin_amdgcn_mfma_f32_16x16x32_bf16(
                    af[i], bfr[j], acc[i][j], 0, 0, 0);
    }

#pragma unroll
    for (int i = 0; i < 4; i++) {
#pragma unroll
        for (int j = 0; j < 4; j++) {
#pragma unroll
            for (int r = 0; r < 4; r++) {
                int m = m0 + wr * 64 + i * 16 + fq * 4 + r;
                int n = n0 + wc * 64 + j * 16 + fr;
                float v = acc[i][j][r];
                if (EPI == 1) {
                    v = silu_f(v);
                    if (n0 < DI) C0[(size_t)m * DI + n] = v;
                    else         C1[(size_t)m * DI + (n - DI)] = v;
                } else {
                    C0[(size_t)m * N + n] = v;
                }
            }
        }
    }
}

// ---------------------------------------------------------------------------
// Per-token: ssm = x_path_row . W_x^T (34 outputs), RMSNorm(B,C), dt_in, lam,
// mean_dt, dtbuf. One block (256 thr) per token.
// ---------------------------------------------------------------------------
__global__ __launch_bounds__(256) void ssm_kernel(
    const float* __restrict__ x_path, const float* __restrict__ W_x,
    const float* __restrict__ W_dt, const float* __restrict__ b_dt,
    const float* __restrict__ B_bias, const float* __restrict__ C_bias,
    const float* __restrict__ B_nw, const float* __restrict__ C_nw,
    float* __restrict__ Bn, float* __restrict__ Cn,
    float* __restrict__ dt_in, float* __restrict__ lam, float* __restrict__ mean_dt,
    float* __restrict__ dtbuf)
{
    __shared__ float red[34 * 4];
    __shared__ float ssm_v[34];
    __shared__ float sh_dtin;
    int tok = blockIdx.x;
    int t = threadIdx.x;
    int w = t >> 6;
    const float* xrow = x_path + (size_t)tok * DI;

    float acc[34];
#pragma unroll
    for (int s = 0; s < 34; s++) acc[s] = 0.f;
#pragma unroll
    for (int j = 0; j < 8; j++) {
        int e = j * 256 + t;
        float xv = xrow[e];
#pragma unroll
        for (int s = 0; s < 34; s++)
            acc[s] = fmaf(xv, W_x[s * DI + e], acc[s]);
    }
#pragma unroll
    for (int s = 0; s < 34; s++) {
        float v = acc[s];
        for (int off = 32; off; off >>= 1) v += __shfl_down(v, off);
        if ((t & 63) == 0) red[s * 4 + w] = v;
    }
    __syncthreads();
    if (t < 34) ssm_v[t] = red[t * 4] + red[t * 4 + 1] + red[t * 4 + 2] + red[t * 4 + 3];
    __syncthreads();
    if (t == 0) {
        float bb, ms;
        ms = 0.f;
        for (int s = 0; s < 16; s++) { bb = ssm_v[s] + B_bias[s]; ms += bb * bb; }
        float r = rsqrtf(ms * (1.f / 16.f) + 1.1920928955078125e-7f);
        for (int s = 0; s < 16; s++) Bn[tok * 16 + s] = (ssm_v[s] + B_bias[s]) * r * B_nw[s];
        ms = 0.f;
        for (int s = 0; s < 16; s++) { bb = ssm_v[16 + s] + C_bias[s]; ms += bb * bb; }
        r = rsqrtf(ms * (1.f / 16.f) + 1.1920928955078125e-7f);
        for (int s = 0; s < 16; s++) Cn[tok * 16 + s] = (ssm_v[16 + s] + C_bias[s]) * r * C_nw[s];
        float dv = ssm_v[32];
        dt_in[tok] = dv;
        sh_dtin = dv;
        lam[tok] = 1.f / (1.f + __expf(-ssm_v[33]));
    }
    __syncthreads();
    float dv = sh_dtin;
    float part = 0.f;
#pragma unroll
    for (int j = 0; j < 8; j++) {
        int e = j * 256 + t;
        float dtv = softplus_f(fmaf(dv, W_dt[e], b_dt[e]));
        dtbuf[(size_t)tok * DI + e] = dtv;
        part += dtv;
    }
    for (int off = 32; off; off >>= 1) part += __shfl_down(part, off);
    __syncthreads();
    if ((t & 63) == 0) red[w] = part;
    __syncthreads();
    if (t == 0) mean_dt[tok] = (red[0] + red[1] + red[2] + red[3]) * (1.f / 2048.f);
}

// ---------------------------------------------------------------------------
__global__ __launch_bounds__(256) void cumsum_kernel(
    const float* __restrict__ mean_dt, double* __restrict__ cum_dt)
{
    __shared__ double tot[256];
    __shared__ double pre[256];
    int b = blockIdx.x, t = threadIdx.x;
    const float* in = mean_dt + b * SEQ;
    double* out = cum_dt + b * SEQ;
    double v[8], sum = 0.0;
#pragma unroll
    for (int i = 0; i < 8; i++) { sum += (double)in[t * 8 + i]; v[i] = sum; }
    tot[t] = sum;
    __syncthreads();
    if (t == 0) { double r = 0.0; for (int i = 0; i < 256; i++) { pre[i] = r; r += tot[i]; } }
    __syncthreads();
    double off = pre[t];
#pragma unroll
    for (int i = 0; i < 8; i++) out[t * 8 + i] = off + v[i];
}

// ---------------------------------------------------------------------------
__global__ __launch_bounds__(256) void rope_kernel(
    const float* __restrict__ Bn, const float* __restrict__ Cn,
    const double* __restrict__ cum_dt, const float* __restrict__ rope_f,
    float* __restrict__ Br, float* __restrict__ Cr)
{
    int g = blockIdx.x * 256 + threadIdx.x;  // 0 .. TOK*8-1
    int tok = g >> 3, i = g & 7;
    double xf = (double)rope_f[i];
    double f = (xf > 0.0) ? xf + log1p(exp(-xf)) : log1p(exp(xf));
    double ang = cum_dt[tok] * f;
    float ca = (float)cos(ang), sa = (float)sin(ang);
    int base = tok * 16 + 2 * i;
    float be = Bn[base], bo = Bn[base + 1];
    Br[base]     = be * ca - bo * sa;
    Br[base + 1] = be * sa + bo * ca;
    float ce = Cn[base], co = Cn[base + 1];
    Cr[base]     = ce * ca - co * sa;
    Cr[base + 1] = ce * sa + co * ca;
}

// ---------------------------------------------------------------------------
// Chunked linear-recurrence scan (A: local scans; B: boundary combine;
// C: re-run + emit y as bf16 for the MFMA out-proj).
// ---------------------------------------------------------------------------
__global__ __launch_bounds__(256) void scan_phaseA(
    const float* __restrict__ x_path, const float* __restrict__ dtbuf,
    const float* __restrict__ Br, const float* __restrict__ lam,
    const float* __restrict__ A_log,
    float* __restrict__ hA, float* __restrict__ PA)
{
    int t = threadIdx.x;
    int s = t & 15, cl = t >> 4;
    int ch = blockIdx.x * 16 + cl;          // 0..4095 = b*DI + e
    int b = ch >> 11, e = ch & (DI - 1);
    int c = blockIdx.y;
    float Ae = fminf(-__expf(A_log[e * 16 + s]), -1e-4f);
    int tok0 = b * SEQ + c * LC;
    const float* xp  = x_path + (size_t)tok0 * DI + e;
    const float* dp  = dtbuf  + (size_t)tok0 * DI + e;
    const float* brp = Br + (size_t)tok0 * 16 + s;
    const float* lp  = lam + tok0;
    float h = 0.f, P = 1.f, Bxp = 0.f;
    if (c > 0) Bxp = brp[-16] * xp[-DI];
    for (int i = 0; i < LC; i++) {
        float dt  = dp[(size_t)i * DI];
        float xv  = xp[(size_t)i * DI];
        float brs = brp[i * 16];
        float lm  = lp[i];
        float dA = __expf(Ae * dt);
        float Bx = brs * xv;
        float u = (c == 0 && i == 0) ? dt * Bx
                                     : (1.f - lm) * dt * dA * Bxp + lm * dt * Bx;
        h = fmaf(dA, h, u);
        P *= dA;
        Bxp = Bx;
    }
    size_t o = (size_t)c * NSTATE + (size_t)ch * 16 + s;
    hA[o] = h;
    PA[o] = P;
}

__global__ __launch_bounds__(256) void scan_phaseB(
    const float* __restrict__ hA, const float* __restrict__ PA,
    float* __restrict__ hin)
{
    int g = blockIdx.x * 256 + threadIdx.x;  // 0..65535
    float h = 0.f;
    hin[g] = 0.f;
    for (int c = 1; c < NCH; c++) {
        size_t o = (size_t)(c - 1) * NSTATE + g;
        h = fmaf(PA[o], h, hA[o]);
        hin[(size_t)c * NSTATE + g] = h;
    }
}

__global__ __launch_bounds__(256) void scan_phaseC(
    const float* __restrict__ x_path, const float* __restrict__ zs,
    const float* __restrict__ dtbuf,
    const float* __restrict__ Br, const float* __restrict__ Cr,
    const float* __restrict__ lam, const float* __restrict__ A_log,
    const float* __restrict__ Dw, const float* __restrict__ hin,
    unsigned short* __restrict__ y)
{
    int t = threadIdx.x;
    int s = t & 15, cl = t >> 4;
    int ch = blockIdx.x * 16 + cl;
    int b = ch >> 11, e = ch & (DI - 1);
    int c = blockIdx.y;
    float Ae = fminf(-__expf(A_log[e * 16 + s]), -1e-4f);
    float Df = Dw[e];
    int tok0 = b * SEQ + c * LC;
    const float* xp  = x_path + (size_t)tok0 * DI + e;
    const float* zp  = zs     + (size_t)tok0 * DI + e;
    const float* dp  = dtbuf  + (size_t)tok0 * DI + e;
    const float* brp = Br + (size_t)tok0 * 16 + s;
    const float* crp = Cr + (size_t)tok0 * 16 + s;
    const float* lp  = lam + tok0;
    unsigned short* yp = y + (size_t)tok0 * DI + e;
    float h = hin[(size_t)c * NSTATE + (size_t)ch * 16 + s];
    float Bxp = 0.f;
    if (c > 0) Bxp = brp[-16] * xp[-DI];
    for (int i = 0; i < LC; i++) {
        float dt  = dp[(size_t)i * DI];
        float xv  = xp[(size_t)i * DI];
        float brs = brp[i * 16];
        float crs = crp[i * 16];
        float lm  = lp[i];
        float dA = __expf(Ae * dt);
        float Bx = brs * xv;
        float u = (c == 0 && i == 0) ? dt * Bx
                                     : (1.f - lm) * dt * dA * Bxp + lm * dt * Bx;
        h = fmaf(dA, h, u);
        Bxp = Bx;
        float p = h * crs;
        p += __shfl_xor(p, 1);
        p += __shfl_xor(p, 2);
        p += __shfl_xor(p, 4);
        p += __shfl_xor(p, 8);
        if (s == 0) {
            float zv = zp[(size_t)i * DI];
            yp[(size_t)i * DI] = f2b((p + xv * Df) * zv);
        }
    }
}

// ---------------------------------------------------------------------------
extern "C" void kernel_launch(void* const* d_in, const int* in_sizes, int n_in,
                              void* d_out, int out_size, void* d_ws, size_t ws_size,
                              hipStream_t stream)
{
    const float* x      = (const float*)d_in[0];
    const float* W_in   = (const float*)d_in[1];
    const float* W_x    = (const float*)d_in[2];
    const float* W_dt   = (const float*)d_in[3];
    const float* b_dt   = (const float*)d_in[4];
    const float* A_log  = (const float*)d_in[5];
    const float* B_bias = (const float*)d_in[6];
    const float* C_bias = (const float*)d_in[7];
    const float* B_nw   = (const float*)d_in[8];
    const float* C_nw   = (const float*)d_in[9];
    const float* rope_f = (const float*)d_in[10];
    const float* Dw     = (const float*)d_in[11];
    const float* W_out  = (const float*)d_in[12];
    float* out = (float*)d_out;          // fp32 output

    char* p = (char*)d_ws;
    const size_t BIGF = (size_t)TOK * DI * 4;         // 33.5 MB
    float* x_path = (float*)(p);                       p += BIGF;
    float* zs     = (float*)(p);                       p += BIGF;
    float* dtbuf  = (float*)(p);                       p += BIGF;
    unsigned short* yb  = (unsigned short*)(p);        p += BIGF / 2;  // bf16
    unsigned short* xb  = (unsigned short*)(p);        p += (size_t)TOK * DM * 2;
    unsigned short* wi16 = (unsigned short*)(p);       p += (size_t)(2 * DI) * DM * 2;
    unsigned short* wo16 = (unsigned short*)(p);       p += (size_t)DM * DI * 2;
    float*  Bn   = (float*)(p);                        p += 262144;
    float*  Cn   = (float*)(p);                        p += 262144;
    float*  Br   = (float*)(p);                        p += 262144;
    float*  Cr   = (float*)(p);                        p += 262144;
    float*  dtin = (float*)(p);                        p += 16384;
    float*  lamv = (float*)(p);                        p += 16384;
    float*  mdt  = (float*)(p);                        p += 16384;
    double* cdt  = (double*)(p);                       p += 32768;
    const size_t SCS = (size_t)NCH * NSTATE * 4;       // 8.4 MB each
    float* hA  = (float*)(p);                          p += SCS;
    float* PA  = (float*)(p);                          p += SCS;
    float* hin = (float*)(p);                          p += SCS;

    // 0. bf16 casts of GEMM inputs
    f2bf_kernel<<<(TOK * DM / 4 + 255) / 256, 256, 0, stream>>>(x, xb, TOK * DM);
    f2bf_kernel<<<(2 * DI * DM / 4 + 255) / 256, 256, 0, stream>>>(W_in, wi16, 2 * DI * DM);
    f2bf_kernel<<<(DM * DI / 4 + 255) / 256, 256, 0, stream>>>(W_out, wo16, DM * DI);
    // 1. xz = x @ W_in^T (MFMA bf16), silu -> x_path, silu(z) (fp32)
    gemm_mfma<1><<<dim3(32, 32), 256, 0, stream>>>(xb, wi16, TOK, 2 * DI, DM, x_path, zs);
    // 2. ssm projections + norms + dt/lam/mean_dt + dtbuf
    ssm_kernel<<<TOK, 256, 0, stream>>>(x_path, W_x, W_dt, b_dt, B_bias, C_bias,
                                        B_nw, C_nw, Bn, Cn, dtin, lamv, mdt, dtbuf);
    // 3. cumsum (fp64)
    cumsum_kernel<<<BSZ, 256, 0, stream>>>(mdt, cdt);
    // 4. rope (fp64 trig)
    rope_kernel<<<(TOK * 8) / 256, 256, 0, stream>>>(Bn, Cn, cdt, rope_f, Br, Cr);
    // 5. chunked scan; phase C emits y as bf16
    scan_phaseA<<<dim3(4096 / 16, NCH), 256, 0, stream>>>(x_path, dtbuf, Br, lamv, A_log, hA, PA);
    scan_phaseB<<<NSTATE / 256, 256, 0, stream>>>(hA, PA, hin);
    scan_phaseC<<<dim3(4096 / 16, NCH), 256, 0, stream>>>(x_path, zs, dtbuf, Br, Cr,
                                                          lamv, A_log, Dw, hin, yb);
    // 6. out = y @ W_out^T (MFMA bf16, fp32 store)
    gemm_mfma<0><<<dim3(DM / 128, TOK / 128), 256, 0, stream>>>(yb, wo16, TOK, DM, DI, out, nullptr);
}

// Round 8
// 392.915 us; speedup vs baseline: 6.5656x; 1.9141x over previous
//
#include <hip/hip_runtime.h>
#include <math.h>

#define TOK 4096      // B*L
#define BSZ 2
#define SEQ 2048
#define DM  1024
#define DI  2048
#define NCH 64        // scan chunks per sequence
#define LC  32        // tokens per chunk (NCH*LC == SEQ)
#define NSTATE 65536  // BSZ*DI*16

typedef __attribute__((ext_vector_type(8))) short bf16x8;      // MFMA A/B frag
typedef __attribute__((ext_vector_type(8))) unsigned short u16x8;
typedef __attribute__((ext_vector_type(4))) float f32x4;       // MFMA C/D frag

__device__ __forceinline__ float softplus_f(float x) {
    return fmaxf(x, 0.f) + __logf(1.f + __expf(-fabsf(x)));
}
__device__ __forceinline__ float silu_f(float x) {
    return x / (1.f + __expf(-x));
}
__device__ __forceinline__ unsigned short f2b(float f) {
    union { float f; unsigned int i; } v; v.f = f;
    unsigned int i = v.i;
    unsigned int r = (i + 0x7fffu + ((i >> 16) & 1u)) >> 16;
    return (unsigned short)r;
}

// ---------------------------------------------------------------------------
__global__ __launch_bounds__(256) void f2bf_kernel(
    const float* __restrict__ in, unsigned short* __restrict__ out, int n)
{
    int g = blockIdx.x * 256 + threadIdx.x;
    int i = g * 4;
    if (i < n) {
        float4 v = *(const float4*)(in + i);
        ushort4 o;
        o.x = f2b(v.x); o.y = f2b(v.y); o.z = f2b(v.z); o.w = f2b(v.w);
        *(ushort4*)(out + i) = o;
    }
}

// W_x [34][2048] -> bf16 padded to [48][2048] (rows 34..47 zero).
__global__ __launch_bounds__(256) void wx_conv_kernel(
    const float* __restrict__ W_x, unsigned short* __restrict__ wx16)
{
    int g = blockIdx.x * 256 + threadIdx.x;    // 0 .. 48*2048-1
    if (g < 48 * 2048) {
        int row = g >> 11;
        wx16[g] = (row < 34) ? f2b(W_x[g]) : (unsigned short)0;
    }
}

// ---------------------------------------------------------------------------
// MFMA GEMM: C[M,N] = A[M,K]*B[N,K]^T, bf16 in, fp32 out. 128x128 tile,
// 4 waves (2x2), 4x4 16x16x32 tiles/wave, BK=32.
// EPI=1: silu; n0<DI -> C0 fp32 + C2 bf16 (x_path), else C1 fp32 (silu z).
// EPI=0: C0[m*N+n].
// ---------------------------------------------------------------------------
template <int EPI>
__global__ __launch_bounds__(256) void gemm_mfma(
    const unsigned short* __restrict__ A, const unsigned short* __restrict__ B,
    int M, int N, int K,
    float* __restrict__ C0, float* __restrict__ C1, unsigned short* __restrict__ C2)
{
    __shared__ unsigned short As[128 * 32];
    __shared__ unsigned short Bs[128 * 32];
    int t = threadIdx.x;
    int lane = t & 63, wave = t >> 6;
    int wr = wave >> 1, wc = wave & 1;
    int m0 = blockIdx.y * 128, n0 = blockIdx.x * 128;

    int srow = t >> 2, skq = t & 3;
    const unsigned short* Ap = A + (size_t)(m0 + srow) * K + skq * 8;
    const unsigned short* Bp = B + (size_t)(n0 + srow) * K + skq * 8;
    int sa = srow * 32 + skq * 8;

    f32x4 acc[4][4];
#pragma unroll
    for (int i = 0; i < 4; i++)
#pragma unroll
        for (int j = 0; j < 4; j++) {
            f32x4 z = {0.f, 0.f, 0.f, 0.f};
            acc[i][j] = z;
        }

    int fr = lane & 15, fq = lane >> 4;

    for (int k0 = 0; k0 < K; k0 += 32) {
        u16x8 a0 = *(const u16x8*)(Ap + k0);
        u16x8 a1 = *(const u16x8*)(Ap + (size_t)64 * K + k0);
        u16x8 b0 = *(const u16x8*)(Bp + k0);
        u16x8 b1 = *(const u16x8*)(Bp + (size_t)64 * K + k0);
        __syncthreads();
        *(u16x8*)&As[sa]           = a0;
        *(u16x8*)&As[sa + 64 * 32] = a1;
        *(u16x8*)&Bs[sa]           = b0;
        *(u16x8*)&Bs[sa + 64 * 32] = b1;
        __syncthreads();
        bf16x8 af[4], bfr[4];
#pragma unroll
        for (int i = 0; i < 4; i++)
            af[i] = *(const bf16x8*)&As[(wr * 64 + i * 16 + fr) * 32 + fq * 8];
#pragma unroll
        for (int j = 0; j < 4; j++)
            bfr[j] = *(const bf16x8*)&Bs[(wc * 64 + j * 16 + fr) * 32 + fq * 8];
#pragma unroll
        for (int i = 0; i < 4; i++)
#pragma unroll
            for (int j = 0; j < 4; j++)
                acc[i][j] = __builtin_amdgcn_mfma_f32_16x16x32_bf16(
                    af[i], bfr[j], acc[i][j], 0, 0, 0);
    }

#pragma unroll
    for (int i = 0; i < 4; i++) {
#pragma unroll
        for (int j = 0; j < 4; j++) {
#pragma unroll
            for (int r = 0; r < 4; r++) {
                int m = m0 + wr * 64 + i * 16 + fq * 4 + r;
                int n = n0 + wc * 64 + j * 16 + fr;
                float v = acc[i][j][r];
                if (EPI == 1) {
                    v = silu_f(v);
                    if (n0 < DI) {
                        C0[(size_t)m * DI + n] = v;
                        C2[(size_t)m * DI + n] = f2b(v);
                    } else {
                        C1[(size_t)m * DI + (n - DI)] = v;
                    }
                } else {
                    C0[(size_t)m * N + n] = v;
                }
            }
        }
    }
}

// ---------------------------------------------------------------------------
// Skinny MFMA GEMM: ssm_v[TOK,48] = xpb[TOK,DI] @ wx16[48,DI]^T. 64-row
// blocks, 4 waves of 16 rows, 3 N-tiles, BK=32.
// ---------------------------------------------------------------------------
__global__ __launch_bounds__(256) void gemm_ssm(
    const unsigned short* __restrict__ xpb, const unsigned short* __restrict__ wx16,
    float* __restrict__ ssm_v)
{
    __shared__ unsigned short As[64 * 32];
    __shared__ unsigned short Bs[48 * 32];
    int t = threadIdx.x, lane = t & 63, wave = t >> 6;
    int m0 = blockIdx.x * 64;
    int srow = t >> 2, skq = t & 3;
    const unsigned short* Ap = xpb + (size_t)(m0 + srow) * DI + skq * 8;
    const unsigned short* Bp = wx16 + (size_t)srow * DI + skq * 8;
    int fr = lane & 15, fq = lane >> 4;

    f32x4 acc[3];
#pragma unroll
    for (int j = 0; j < 3; j++) { f32x4 z = {0.f,0.f,0.f,0.f}; acc[j] = z; }

    for (int k0 = 0; k0 < DI; k0 += 32) {
        u16x8 av = *(const u16x8*)(Ap + k0);
        u16x8 bv = {0,0,0,0,0,0,0,0};
        if (srow < 48) bv = *(const u16x8*)(Bp + k0);
        __syncthreads();
        *(u16x8*)&As[srow * 32 + skq * 8] = av;
        if (srow < 48) *(u16x8*)&Bs[srow * 32 + skq * 8] = bv;
        __syncthreads();
        bf16x8 af = *(const bf16x8*)&As[(wave * 16 + fr) * 32 + fq * 8];
#pragma unroll
        for (int j = 0; j < 3; j++) {
            bf16x8 bf = *(const bf16x8*)&Bs[(j * 16 + fr) * 32 + fq * 8];
            acc[j] = __builtin_amdgcn_mfma_f32_16x16x32_bf16(af, bf, acc[j], 0, 0, 0);
        }
    }
#pragma unroll
    for (int j = 0; j < 3; j++)
#pragma unroll
        for (int r = 0; r < 4; r++) {
            int m = m0 + wave * 16 + fq * 4 + r;
            ssm_v[(size_t)m * 48 + j * 16 + fr] = acc[j][r];
        }
}

// ---------------------------------------------------------------------------
// Per-token RMSNorm(B,C) + dt_in + lam from ssm_v. One thread per token.
// ---------------------------------------------------------------------------
__global__ __launch_bounds__(256) void norm_kernel(
    const float* __restrict__ ssm_v,
    const float* __restrict__ B_bias, const float* __restrict__ C_bias,
    const float* __restrict__ B_nw, const float* __restrict__ C_nw,
    float* __restrict__ Bn, float* __restrict__ Cn,
    float* __restrict__ dt_in, float* __restrict__ lam)
{
    int tok = blockIdx.x * 256 + threadIdx.x;
    const float* v = ssm_v + (size_t)tok * 48;
    float bb[16], ms = 0.f;
#pragma unroll
    for (int s = 0; s < 16; s++) { bb[s] = v[s] + B_bias[s]; ms += bb[s] * bb[s]; }
    float r = rsqrtf(ms * (1.f / 16.f) + 1.1920928955078125e-7f);
#pragma unroll
    for (int s = 0; s < 16; s++) Bn[tok * 16 + s] = bb[s] * r * B_nw[s];
    ms = 0.f;
#pragma unroll
    for (int s = 0; s < 16; s++) { bb[s] = v[16 + s] + C_bias[s]; ms += bb[s] * bb[s]; }
    r = rsqrtf(ms * (1.f / 16.f) + 1.1920928955078125e-7f);
#pragma unroll
    for (int s = 0; s < 16; s++) Cn[tok * 16 + s] = bb[s] * r * C_nw[s];
    dt_in[tok] = v[32];
    lam[tok] = 1.f / (1.f + __expf(-v[33]));
}

// ---------------------------------------------------------------------------
// mean_dt[tok] = mean_e softplus(dt_in[tok]*W_dt[e]+b_dt[e]). Block per token.
// ---------------------------------------------------------------------------
__global__ __launch_bounds__(256) void dtmean_kernel(
    const float* __restrict__ dt_in, const float* __restrict__ W_dt,
    const float* __restrict__ b_dt, float* __restrict__ mean_dt)
{
    __shared__ float red[4];
    int tok = blockIdx.x, t = threadIdx.x;
    float dti = dt_in[tok];
    float part = 0.f;
#pragma unroll
    for (int j = 0; j < 8; j++) {
        int e = j * 256 + t;
        part += softplus_f(fmaf(dti, W_dt[e], b_dt[e]));
    }
    for (int off = 32; off; off >>= 1) part += __shfl_down(part, off);
    if ((t & 63) == 0) red[t >> 6] = part;
    __syncthreads();
    if (t == 0) mean_dt[tok] = (red[0] + red[1] + red[2] + red[3]) * (1.f / 2048.f);
}

// ---------------------------------------------------------------------------
__global__ __launch_bounds__(256) void cumsum_kernel(
    const float* __restrict__ mean_dt, double* __restrict__ cum_dt)
{
    __shared__ double tot[256];
    __shared__ double pre[256];
    int b = blockIdx.x, t = threadIdx.x;
    const float* in = mean_dt + b * SEQ;
    double* out = cum_dt + b * SEQ;
    double v[8], sum = 0.0;
#pragma unroll
    for (int i = 0; i < 8; i++) { sum += (double)in[t * 8 + i]; v[i] = sum; }
    tot[t] = sum;
    __syncthreads();
    if (t == 0) { double r = 0.0; for (int i = 0; i < 256; i++) { pre[i] = r; r += tot[i]; } }
    __syncthreads();
    double off = pre[t];
#pragma unroll
    for (int i = 0; i < 8; i++) out[t * 8 + i] = off + v[i];
}

// ---------------------------------------------------------------------------
__global__ __launch_bounds__(256) void rope_kernel(
    const float* __restrict__ Bn, const float* __restrict__ Cn,
    const double* __restrict__ cum_dt, const float* __restrict__ rope_f,
    float* __restrict__ Br, float* __restrict__ Cr)
{
    int g = blockIdx.x * 256 + threadIdx.x;  // 0 .. TOK*8-1
    int tok = g >> 3, i = g & 7;
    double xf = (double)rope_f[i];
    double f = (xf > 0.0) ? xf + log1p(exp(-xf)) : log1p(exp(xf));
    double ang = cum_dt[tok] * f;
    float ca = (float)cos(ang), sa = (float)sin(ang);
    int base = tok * 16 + 2 * i;
    float be = Bn[base], bo = Bn[base + 1];
    Br[base]     = be * ca - bo * sa;
    Br[base + 1] = be * sa + bo * ca;
    float ce = Cn[base], co = Cn[base + 1];
    Cr[base]     = ce * ca - co * sa;
    Cr[base + 1] = ce * sa + co * ca;
}

// ---------------------------------------------------------------------------
// Chunked scan, one THREAD per channel: h[16]/Bxp[16]/Ae[16] in registers,
// no shuffles; x/z coalesced per-lane, Br/Cr wave-broadcast float4 loads;
// dt recomputed inline (no dtbuf).
// ---------------------------------------------------------------------------
__global__ __launch_bounds__(256) void scan_phaseA(
    const float* __restrict__ x_path,
    const float* __restrict__ Br, const float* __restrict__ dt_in,
    const float* __restrict__ lam, const float* __restrict__ W_dt,
    const float* __restrict__ b_dt, const float* __restrict__ A_log,
    float* __restrict__ hA, float* __restrict__ PA)
{
    int ch = blockIdx.x * 256 + threadIdx.x;   // 0..4095 = b*DI + e
    int b = ch >> 11, e = ch & (DI - 1);
    int c = blockIdx.y;
    float wdt = W_dt[e], bdt = b_dt[e];
    float Ae[16], h[16], P[16], Bxp[16];
#pragma unroll
    for (int q = 0; q < 4; q++) {
        float4 al = *(const float4*)(A_log + e * 16 + q * 4);
        Ae[q*4+0] = fminf(-__expf(al.x), -1e-4f);
        Ae[q*4+1] = fminf(-__expf(al.y), -1e-4f);
        Ae[q*4+2] = fminf(-__expf(al.z), -1e-4f);
        Ae[q*4+3] = fminf(-__expf(al.w), -1e-4f);
    }
#pragma unroll
    for (int s = 0; s < 16; s++) { h[s] = 0.f; P[s] = 1.f; Bxp[s] = 0.f; }
    int tok0 = b * SEQ + c * LC;
    if (c > 0) {
        float xvp = x_path[(size_t)(tok0 - 1) * DI + e];
#pragma unroll
        for (int q = 0; q < 4; q++) {
            float4 bq = *(const float4*)(Br + (size_t)(tok0 - 1) * 16 + q * 4);
            Bxp[q*4+0] = bq.x * xvp; Bxp[q*4+1] = bq.y * xvp;
            Bxp[q*4+2] = bq.z * xvp; Bxp[q*4+3] = bq.w * xvp;
        }
    }
    for (int i = 0; i < LC; i++) {
        int tok = tok0 + i;
        float xv  = x_path[(size_t)tok * DI + e];
        float dti = dt_in[tok];
        float lm  = lam[tok];
        float dt  = softplus_f(fmaf(dti, wdt, bdt));
        float ac = lm * dt, bc = (1.f - lm) * dt;
        bool first = (c == 0 && i == 0);
#pragma unroll
        for (int q = 0; q < 4; q++) {
            float4 bq = *(const float4*)(Br + (size_t)tok * 16 + q * 4);
            float brv[4] = {bq.x, bq.y, bq.z, bq.w};
#pragma unroll
            for (int r = 0; r < 4; r++) {
                int s = q * 4 + r;
                float dA = __expf(Ae[s] * dt);
                float Bx = brv[r] * xv;
                float u = first ? dt * Bx : fmaf(bc * dA, Bxp[s], ac * Bx);
                h[s] = fmaf(dA, h[s], u);
                P[s] *= dA;
                Bxp[s] = Bx;
            }
        }
    }
    size_t o = (size_t)c * NSTATE + (size_t)ch * 16;
#pragma unroll
    for (int q = 0; q < 4; q++) {
        *(float4*)&hA[o + q * 4] = make_float4(h[q*4], h[q*4+1], h[q*4+2], h[q*4+3]);
        *(float4*)&PA[o + q * 4] = make_float4(P[q*4], P[q*4+1], P[q*4+2], P[q*4+3]);
    }
}

__global__ __launch_bounds__(256) void scan_phaseB(
    const float* __restrict__ hA, const float* __restrict__ PA,
    float* __restrict__ hin)
{
    int g = blockIdx.x * 256 + threadIdx.x;  // 0..NSTATE-1
    float h = 0.f;
    hin[g] = 0.f;
    for (int c = 1; c < NCH; c++) {
        size_t o = (size_t)(c - 1) * NSTATE + g;
        h = fmaf(PA[o], h, hA[o]);
        hin[(size_t)c * NSTATE + g] = h;
    }
}

__global__ __launch_bounds__(256) void scan_phaseC(
    const float* __restrict__ x_path, const float* __restrict__ zs,
    const float* __restrict__ Br, const float* __restrict__ Cr,
    const float* __restrict__ dt_in, const float* __restrict__ lam,
    const float* __restrict__ W_dt, const float* __restrict__ b_dt,
    const float* __restrict__ A_log, const float* __restrict__ Dw,
    const float* __restrict__ hin, unsigned short* __restrict__ y)
{
    int ch = blockIdx.x * 256 + threadIdx.x;
    int b = ch >> 11, e = ch & (DI - 1);
    int c = blockIdx.y;
    float wdt = W_dt[e], bdt = b_dt[e], Df = Dw[e];
    float Ae[16], h[16], Bxp[16];
#pragma unroll
    for (int q = 0; q < 4; q++) {
        float4 al = *(const float4*)(A_log + e * 16 + q * 4);
        Ae[q*4+0] = fminf(-__expf(al.x), -1e-4f);
        Ae[q*4+1] = fminf(-__expf(al.y), -1e-4f);
        Ae[q*4+2] = fminf(-__expf(al.z), -1e-4f);
        Ae[q*4+3] = fminf(-__expf(al.w), -1e-4f);
    }
    size_t ho = (size_t)c * NSTATE + (size_t)ch * 16;
#pragma unroll
    for (int q = 0; q < 4; q++) {
        float4 hq = *(const float4*)&hin[ho + q * 4];
        h[q*4+0] = hq.x; h[q*4+1] = hq.y; h[q*4+2] = hq.z; h[q*4+3] = hq.w;
    }
#pragma unroll
    for (int s = 0; s < 16; s++) Bxp[s] = 0.f;
    int tok0 = b * SEQ + c * LC;
    if (c > 0) {
        float xvp = x_path[(size_t)(tok0 - 1) * DI + e];
#pragma unroll
        for (int q = 0; q < 4; q++) {
            float4 bq = *(const float4*)(Br + (size_t)(tok0 - 1) * 16 + q * 4);
            Bxp[q*4+0] = bq.x * xvp; Bxp[q*4+1] = bq.y * xvp;
            Bxp[q*4+2] = bq.z * xvp; Bxp[q*4+3] = bq.w * xvp;
        }
    }
    for (int i = 0; i < LC; i++) {
        int tok = tok0 + i;
        float xv  = x_path[(size_t)tok * DI + e];
        float zv  = zs[(size_t)tok * DI + e];
        float dti = dt_in[tok];
        float lm  = lam[tok];
        float dt  = softplus_f(fmaf(dti, wdt, bdt));
        float ac = lm * dt, bc = (1.f - lm) * dt;
        bool first = (c == 0 && i == 0);
        float acc = 0.f;
#pragma unroll
        for (int q = 0; q < 4; q++) {
            float4 bq = *(const float4*)(Br + (size_t)tok * 16 + q * 4);
            float4 cq = *(const float4*)(Cr + (size_t)tok * 16 + q * 4);
            float brv[4] = {bq.x, bq.y, bq.z, bq.w};
            float crv[4] = {cq.x, cq.y, cq.z, cq.w};
#pragma unroll
            for (int r = 0; r < 4; r++) {
                int s = q * 4 + r;
                float dA = __expf(Ae[s] * dt);
                float Bx = brv[r] * xv;
                float u = first ? dt * Bx : fmaf(bc * dA, Bxp[s], ac * Bx);
                h[s] = fmaf(dA, h[s], u);
                Bxp[s] = Bx;
                acc = fmaf(h[s], crv[r], acc);
            }
        }
        y[(size_t)tok * DI + e] = f2b((acc + xv * Df) * zv);
    }
}

// ---------------------------------------------------------------------------
extern "C" void kernel_launch(void* const* d_in, const int* in_sizes, int n_in,
                              void* d_out, int out_size, void* d_ws, size_t ws_size,
                              hipStream_t stream)
{
    const float* x      = (const float*)d_in[0];
    const float* W_in   = (const float*)d_in[1];
    const float* W_x    = (const float*)d_in[2];
    const float* W_dt   = (const float*)d_in[3];
    const float* b_dt   = (const float*)d_in[4];
    const float* A_log  = (const float*)d_in[5];
    const float* B_bias = (const float*)d_in[6];
    const float* C_bias = (const float*)d_in[7];
    const float* B_nw   = (const float*)d_in[8];
    const float* C_nw   = (const float*)d_in[9];
    const float* rope_f = (const float*)d_in[10];
    const float* Dw     = (const float*)d_in[11];
    const float* W_out  = (const float*)d_in[12];
    float* out = (float*)d_out;          // fp32 output

    char* p = (char*)d_ws;
    const size_t BIGF = (size_t)TOK * DI * 4;          // 33.5 MB
    float* x_path = (float*)(p);                       p += BIGF;
    float* zs     = (float*)(p);                       p += BIGF;
    unsigned short* yb   = (unsigned short*)(p);       p += BIGF / 2;
    unsigned short* xpb  = (unsigned short*)(p);       p += BIGF / 2;
    unsigned short* xb   = (unsigned short*)(p);       p += (size_t)TOK * DM * 2;
    unsigned short* wi16 = (unsigned short*)(p);       p += (size_t)(2 * DI) * DM * 2;
    unsigned short* wo16 = (unsigned short*)(p);       p += (size_t)DM * DI * 2;
    unsigned short* wx16 = (unsigned short*)(p);       p += 48 * 2048 * 2;
    float*  ssm_v = (float*)(p);                       p += (size_t)TOK * 48 * 4;
    float*  Bn   = (float*)(p);                        p += 262144;
    float*  Cn   = (float*)(p);                        p += 262144;
    float*  Br   = (float*)(p);                        p += 262144;
    float*  Cr   = (float*)(p);                        p += 262144;
    float*  dtin = (float*)(p);                        p += 16384;
    float*  lamv = (float*)(p);                        p += 16384;
    float*  mdt  = (float*)(p);                        p += 16384;
    double* cdt  = (double*)(p);                       p += 32768;
    const size_t SCS = (size_t)NCH * NSTATE * 4;       // 16.8 MB each
    float* hA  = (float*)(p);                          p += SCS;
    float* PA  = (float*)(p);                          p += SCS;
    float* hin = (float*)(p);                          p += SCS;

    // 0. bf16 casts
    f2bf_kernel<<<(TOK * DM / 4 + 255) / 256, 256, 0, stream>>>(x, xb, TOK * DM);
    f2bf_kernel<<<(2 * DI * DM / 4 + 255) / 256, 256, 0, stream>>>(W_in, wi16, 2 * DI * DM);
    f2bf_kernel<<<(DM * DI / 4 + 255) / 256, 256, 0, stream>>>(W_out, wo16, DM * DI);
    wx_conv_kernel<<<(48 * 2048 + 255) / 256, 256, 0, stream>>>(W_x, wx16);
    // 1. xz = x @ W_in^T (MFMA), silu -> x_path fp32 + xpb bf16, zs fp32
    gemm_mfma<1><<<dim3(32, 32), 256, 0, stream>>>(xb, wi16, TOK, 2 * DI, DM,
                                                   x_path, zs, xpb);
    // 2. ssm projection (skinny MFMA) + per-token norms
    gemm_ssm<<<TOK / 64, 256, 0, stream>>>(xpb, wx16, ssm_v);
    norm_kernel<<<TOK / 256, 256, 0, stream>>>(ssm_v, B_bias, C_bias, B_nw, C_nw,
                                               Bn, Cn, dtin, lamv);
    dtmean_kernel<<<TOK, 256, 0, stream>>>(dtin, W_dt, b_dt, mdt);
    // 3. cumsum (fp64), 4. rope (fp64 trig)
    cumsum_kernel<<<BSZ, 256, 0, stream>>>(mdt, cdt);
    rope_kernel<<<(TOK * 8) / 256, 256, 0, stream>>>(Bn, Cn, cdt, rope_f, Br, Cr);
    // 5. chunked scan (register-resident states, no shuffles)
    scan_phaseA<<<dim3(4096 / 256, NCH), 256, 0, stream>>>(x_path, Br, dtin, lamv,
                                                           W_dt, b_dt, A_log, hA, PA);
    scan_phaseB<<<NSTATE / 256, 256, 0, stream>>>(hA, PA, hin);
    scan_phaseC<<<dim3(4096 / 256, NCH), 256, 0, stream>>>(x_path, zs, Br, Cr, dtin, lamv,
                                                           W_dt, b_dt, A_log, Dw, hin, yb);
    // 6. out = y @ W_out^T (MFMA, fp32 store)
    gemm_mfma<0><<<dim3(DM / 128, TOK / 128), 256, 0, stream>>>(yb, wo16, TOK, DM, DI,
                                                                out, nullptr, nullptr);
}